// Round 14
// baseline (623.439 us; speedup 1.0000x reference)
//
#include <hip/hip_runtime.h>
#include <hip/hip_bf16.h>
#include <math.h>

// Between layers: NHWC bf16 RAW (pre-BN) [B][256*256][136] (ch=ci*8+o, pad->136).
// BN+ReLU applied during the NEXT layer's staging from fused batch stats.
#define HW 65536
#define WID 256
#define NOR 8
#define PLANE_C (NOR * HW)          // 524288
#define PLANE_B (16 * NOR * HW)     // 8388608
#define BN_N 1048576.0f
#define NHWC_STRIDE 136

typedef __attribute__((ext_vector_type(8)))  short  short8;
typedef __attribute__((ext_vector_type(4)))  short  short4v;
typedef __attribute__((ext_vector_type(16))) float  float16;
typedef __attribute__((ext_vector_type(4)))  float  float4v;

__device__ __forceinline__ float b2f(short s) {
    union { unsigned int u; float f; } c;
    c.u = ((unsigned int)(unsigned short)s) << 16;
    return c.f;
}
__device__ __forceinline__ short f2b(float f) {
    union { __hip_bfloat16 h; short s; } c;
    c.h = __float2bfloat16(f);
    return c.s;
}
__device__ __forceinline__ float ldv(const void* p, int i, int isbf) {
    return isbf ? b2f(((const short*)p)[i]) : ((const float*)p)[i];
}

// ---- detect dtype + convert the 176 BN/fw scalars (one block) ----
__global__ void detect_cvt_k(const void* x, const void* fw,
                             const void* g0, const void* b0, const void* g1, const void* b1,
                             const void* g2, const void* b2, const void* g3, const void* b3,
                             const void* g4, const void* b4,
                             float* __restrict__ gbF, float* __restrict__ fwF,
                             int* __restrict__ flag) {
    __shared__ int bad;
    if (threadIdx.x == 0) bad = 0;
    __syncthreads();
    const __hip_bfloat16* p = (const __hip_bfloat16*)x;
    for (int i = threadIdx.x; i < 4096; i += 256) {
        float v = __bfloat162float(p[i]);
        if (!(fabsf(v) < 1e4f)) atomicOr(&bad, 1);
    }
    __syncthreads();
    int isbf = bad ? 0 : 1;
    if (threadIdx.x == 0) *flag = isbf;
    int t = threadIdx.x;
    if (t < 160) {
        const void* srcs[10] = {g0, b0, g1, b1, g2, b2, g3, b3, g4, b4};
        gbF[t] = ldv(srcs[t >> 4], t & 15, isbf);
    } else if (t < 176) {
        fwF[t - 160] = ldv(fw, t - 160, isbf);
    }
}

// ---- bilinear kernel rotation, flag-branched source (same math as R2..R13) ----
__device__ float rot_sample_g(const void* __restrict__ W, int isbf, int k, float theta,
                              int i, int j) {
    float c = 0.5f * (float)(k - 1);
    float ys = (float)i - c, xs = (float)j - c;
    float cs = cosf(theta), sn = sinf(theta);
    float sy = cs * ys - sn * xs + c;
    float sx = sn * ys + cs * xs + c;
    float fy = floorf(sy), fx = floorf(sx);
    int y0 = (int)fy, x0 = (int)fx;
    float wy = sy - fy, wx = sx - fx;
    float v00 = (y0 >= 0 && y0 < k && x0 >= 0 && x0 < k)                 ? ldv(W, y0 * k + x0, isbf)           : 0.f;
    float v01 = (y0 >= 0 && y0 < k && x0 + 1 >= 0 && x0 + 1 < k)         ? ldv(W, y0 * k + x0 + 1, isbf)       : 0.f;
    float v10 = (y0 + 1 >= 0 && y0 + 1 < k && x0 >= 0 && x0 < k)         ? ldv(W, (y0 + 1) * k + x0, isbf)     : 0.f;
    float v11 = (y0 + 1 >= 0 && y0 + 1 < k && x0 + 1 >= 0 && x0 + 1 < k) ? ldv(W, (y0 + 1) * k + x0 + 1, isbf) : 0.f;
    return v00 * (1 - wy) * (1 - wx) + v01 * (1 - wy) * wx
         + v10 * wy * (1 - wx) + v11 * wy * wx;
}

__device__ __forceinline__ float theta_of(int m) {
    return (6.2831855f * (float)m) / 8.0f;
}

__device__ __forceinline__ int mirror(int i) {
    i = i < 0 ? -i : i;
    return i >= WID ? (2 * WID - 2 - i) : i;
}

// ---- MEGA-PACK (flag-branched raw weights) + all 5 layer stats zeroed ----
// Blift[n=c*8+o][k=ci*49+s pad 160]; Bg[q(4)][s(25)][kc4(4)][n(128)][j(8)],
// ch=q*32+kc4*8+j; B1[n][ch].
#define PK_BLIFT 20480
#define PK_BG 409600
#define PK_TOTAL (PK_BLIFT + 3 * PK_BG + 16384)
__global__ void mega_pack_k(const void* __restrict__ lw, const void* __restrict__ w1,
                            const void* __restrict__ w2, const void* __restrict__ w3,
                            const void* __restrict__ w4,
                            __hip_bfloat16* __restrict__ Blift, __hip_bfloat16* __restrict__ Bg1,
                            __hip_bfloat16* __restrict__ Bg2, __hip_bfloat16* __restrict__ Bg3,
                            __hip_bfloat16* __restrict__ B1, float* __restrict__ statsL,
                            const int* __restrict__ flag) {
    int idx = blockIdx.x * 256 + threadIdx.x;
    if (idx < 160) statsL[idx] = 0.f;
    if (idx >= PK_TOTAL) return;
    int isbf = *flag;
    if (idx < PK_BLIFT) {
        int n = idx / 160, k = idx % 160;
        float v = 0.f;
        if (k < 147) {
            int c = n >> 3, o = n & 7;
            int ci = k / 49, s = k % 49;
            v = rot_sample_g(isbf ? (const void*)((const short*)lw + (c * 3 + ci) * 49)
                                  : (const void*)((const float*)lw + (c * 3 + ci) * 49),
                             isbf, 7, theta_of(o), s / 7, s % 7);
        }
        Blift[idx] = __float2bfloat16(v);
        return;
    }
    idx -= PK_BLIFT;
    if (idx < 3 * PK_BG) {
        int l = idx / PK_BG;
        int r = idx - l * PK_BG;
        const void* w = (l == 0) ? w1 : ((l == 1) ? w2 : w3);
        __hip_bfloat16* Bg = (l == 0) ? Bg1 : ((l == 1) ? Bg2 : Bg3);
        int j = r & 7;
        int n = (r >> 3) & 127;
        int kc4 = (r >> 10) & 3;
        int sq = r >> 12;
        int s = sq % 25, q = sq / 25;
        int ch = q * 32 + kc4 * 8 + j;
        int co = n >> 3, m = n & 7, ci = ch >> 3, o = ch & 7;
        int oo = (o - m + 8) & 7;
        int off = ((co * 16 + ci) * 8 + oo) * 25;
        const void* wp = isbf ? (const void*)((const short*)w + off)
                              : (const void*)((const float*)w + off);
        Bg[r] = __float2bfloat16(rot_sample_g(wp, isbf, 5, theta_of(m), s / 5, s % 5));
        return;
    }
    idx -= 3 * PK_BG;
    {
        int n = idx >> 7, ch = idx & 127;
        int co = n >> 3, m = n & 7, ci = ch >> 3, o = ch & 7;
        B1[idx] = __float2bfloat16(ldv(w4, (co * 16 + ci) * 8 + ((o - m + 8) & 7), isbf));
    }
}

// BN partial-sum reduction (8-acc 32x32 variant), verified R6..R13.
__device__ __forceinline__ void stats_reduce8(const float16* acc, int lane, int l31,
                                              float* sred) {
#pragma unroll
    for (int nt = 0; nt < 4; nt++) {
        float sv = 0.f, s2v = 0.f;
#pragma unroll
        for (int g = 0; g < 2; g++)
#pragma unroll
            for (int r = 0; r < 16; r++) {
                float v = acc[g * 4 + nt][r];
                sv += v;
                s2v += v * v;
            }
#pragma unroll
        for (int off = 1; off <= 4; off <<= 1) {
            sv += __shfl_xor(sv, off);
            s2v += __shfl_xor(s2v, off);
        }
        sv += __shfl_xor(sv, 32);
        s2v += __shfl_xor(s2v, 32);
        if ((lane & 39) == 0) {
            int c = nt * 4 + (l31 >> 3);
            atomicAdd(&sred[c], sv);
            atomicAdd(&sred[16 + c], s2v);
        }
    }
}

// ---- FUSED lift (R11/R13, unchanged) ----
__global__ __launch_bounds__(256, 2) void lift_fused_k(const void* __restrict__ x,
                                                       const __hip_bfloat16* __restrict__ Bh,
                                                       __hip_bfloat16* __restrict__ nh_out,
                                                       float* __restrict__ stats,
                                                       const int* __restrict__ flag) {
    __shared__ float Xs[3 * 484];
    __shared__ short tb[32768];
    __shared__ float sred[32];
    const short* B = (const short*)Bh;
    int tid = threadIdx.x;
    if (tid < 32) sred[tid] = 0.f;
    int isbf = *flag;
    int tile = blockIdx.x;
    int b = blockIdx.y;
    int tx0 = (tile & 15) << 4, ty0 = (tile >> 4) << 4;
    for (int i = tid; i < 1452; i += 256) {
        int ci = i / 484, p = i - ci * 484;
        int yl = p / 22, xl = p - yl * 22;
        int gy = mirror(ty0 - 3 + yl), gx = mirror(tx0 - 3 + xl);
        Xs[i] = ldv(x, (int)(((size_t)b * 3 + ci) * HW) + gy * WID + gx, isbf);
    }
    __syncthreads();
    int wave = tid >> 6, lane = tid & 63;
    int l31 = lane & 31, half = lane >> 5;
    float16 acc[8];
#pragma unroll
    for (int i = 0; i < 8; i++) acc[i] = (float16)0.f;
    int pxl0 = wave * 64 + l31;
    int py0 = pxl0 >> 4, px0 = pxl0 & 15;
    int py1 = (pxl0 + 32) >> 4, px1 = (pxl0 + 32) & 15;
    const short* bp = B + (size_t)l31 * 160 + half * 8;
#pragma unroll
    for (int ks = 0; ks < 10; ks++) {
        short8 a0, a1;
#pragma unroll
        for (int j = 0; j < 8; j++) {
            int k = ks * 16 + half * 8 + j;
            float v0 = 0.f, v1 = 0.f;
            if (k < 147) {
                int ci = (k < 49) ? 0 : ((k < 98) ? 1 : 2);
                int s = k - ci * 49;
                int sy = s / 7, sx = s - sy * 7;
                v0 = Xs[ci * 484 + (py0 + sy) * 22 + px0 + sx];
                v1 = Xs[ci * 484 + (py1 + sy) * 22 + px1 + sx];
            }
            a0[j] = f2b(v0);
            a1[j] = f2b(v1);
        }
#pragma unroll
        for (int nt = 0; nt < 4; nt++) {
            short8 bb = *(const short8*)(bp + nt * 32 * 160 + ks * 16);
            acc[nt]     = __builtin_amdgcn_mfma_f32_32x32x16_bf16(a0, bb, acc[nt], 0, 0, 0);
            acc[4 + nt] = __builtin_amdgcn_mfma_f32_32x32x16_bf16(a1, bb, acc[4 + nt], 0, 0, 0);
        }
    }
#pragma unroll
    for (int g = 0; g < 2; g++)
#pragma unroll
        for (int nt = 0; nt < 4; nt++) {
            int ch = nt * 32 + l31;
#pragma unroll
            for (int r4 = 0; r4 < 4; r4++) {
                int pxb = wave * 64 + g * 32 + 8 * r4 + 4 * half;
#pragma unroll
                for (int i = 0; i < 4; i++)
                    tb[(pxb + i) * 128 + ch] = f2b(acc[g * 4 + nt][r4 * 4 + i]);
            }
        }
    __syncthreads();
    short* outp = (short*)nh_out + (size_t)b * HW * NHWC_STRIDE;
    for (int i = tid; i < 4096; i += 256) {
        int pxl = i >> 4, seg = i & 15;
        int y = ty0 + (pxl >> 4), xx = tx0 + (pxl & 15);
        *(short8*)(outp + ((size_t)y * WID + xx) * NHWC_STRIDE + seg * 8) =
            *(const short8*)&tb[pxl * 128 + seg * 8];
    }
    stats_reduce8(acc, lane, l31, sred);
    __syncthreads();
    if (tid < 16) {
        atomicAdd(&stats[tid * 2], sred[tid]);
        atomicAdd(&stats[tid * 2 + 1], sred[16 + tid]);
    }
}

// gconv GEMM R14: combine R9's occupancy (4x4 acc = 64 AGPR -> 3 blocks/CU)
// with R12/R13's low reads/MFMA via dx-outer row caching: per (q,dx0) load
// a[8] rows once, reuse across 5 dy -> 28 loads per 80 MFMA (0.35 r/M).
// 1024 blocks (XCD band swizzle, nhalf split), wave = 64 px (4 rows) x 64 n.
// A-halo per q-quarter (32 ch) in LDS; B via L1; barrier-free (q,dx,dy) loop;
// BN(prev) at staging; raw NHWC out via LDS transpose; fused stats.
__global__ __launch_bounds__(256, 3) void gconv_mfma_k(const __hip_bfloat16* __restrict__ nh_in,
                                                       const __hip_bfloat16* __restrict__ Bgh,
                                                       __hip_bfloat16* __restrict__ nh_out,
                                                       const float* __restrict__ statsPrev,
                                                       const float* __restrict__ gPrev,
                                                       const float* __restrict__ bPrev,
                                                       float* __restrict__ statsNew) {
    __shared__ short Au[16384];   // union: halo [kc4][441][8] (14112 used) | transpose [256][64]
    __shared__ float ssl[32];
    __shared__ float sred[32];
    const short* nhwc = (const short*)nh_in;
    const short* Bg = (const short*)Bgh;
    int bid = blockIdx.x;              // 0..1023
    int xcd = bid & 7, q2 = bid >> 3;
    int nhf = q2 & 1, qt = q2 >> 1;
    int b = xcd >> 2, band = xcd & 3;
    int tx0 = (qt & 15) << 4;
    int ty0 = (band << 6) + ((qt >> 4) << 4);
    int tid = threadIdx.x;
    if (tid < 32) sred[tid] = 0.f;
    if (tid < 16) {
        float mean = statsPrev[tid * 2] / BN_N;
        float var = statsPrev[tid * 2 + 1] / BN_N - mean * mean;
        float sc = gPrev[tid] * rsqrtf(var + 1e-5f);
        ssl[tid * 2] = sc;
        ssl[tid * 2 + 1] = bPrev[tid] - mean * sc;
    }
    int w = tid >> 6, lane = tid & 63;   // w = row-group: rows 4w..4w+3
    int l15 = lane & 15, l4 = lane >> 4;
    float4v acc[16];
#pragma unroll
    for (int i = 0; i < 16; i++) acc[i] = (float4v)0.f;
    const size_t bbase = (size_t)b * HW;
    const int nb = nhf << 6;

    for (int q = 0; q < 4; q++) {
        __syncthreads();   // Au reuse guard (+ ssl/sred init at q=0)
        for (int i = tid; i < 1600; i += 256) {
            int kc = i / 400, p = i - kc * 400;
            int yl = p / 20, xl = p - yl * 20;
            int gy = mirror(ty0 - 2 + yl);
            int gx = mirror(tx0 - 2 + xl);
            short8 raw = *(const short8*)(nhwc + (bbase + gy * WID + gx) * NHWC_STRIDE
                                          + q * 32 + kc * 8);
            int c = q * 4 + kc;
            float sc = ssl[c * 2], sh = ssl[c * 2 + 1];
            short8 ov;
#pragma unroll
            for (int e = 0; e < 8; e++)
                ov[e] = f2b(fmaxf(fmaf(b2f(raw[e]), sc, sh), 0.f));
            *(short8*)&Au[(kc * 441 + yl * 21 + xl) * 8] = ov;
        }
        __syncthreads();
        int kcol = l4 * 441;
#pragma unroll
        for (int dx0 = 0; dx0 < 5; dx0++) {
            // 8 row-frags (rows 4w-2 .. 4w+5 in halo coords) cover all dy
            int base0 = kcol + (w << 2) * 21 + (l15 + dx0);
            short8 a[8];
#pragma unroll
            for (int rr = 0; rr < 8; rr++)
                a[rr] = *(const short8*)&Au[(base0 + rr * 21) * 8];
#pragma unroll
            for (int dy0 = 0; dy0 < 5; dy0++) {
                int s = dy0 * 5 + dx0;
                const short* brow = Bg
                    + ((size_t)(((q * 25 + s) << 2) + l4) * 128 + nb + l15) * 8;
#pragma unroll
                for (int nt = 0; nt < 4; nt++) {
                    short8 bb = *(const short8*)(brow + nt * 128);
#pragma unroll
                    for (int r = 0; r < 4; r++)
                        acc[r * 4 + nt] = __builtin_amdgcn_mfma_f32_16x16x32_bf16(
                            a[dy0 + r], bb, acc[r * 4 + nt], 0, 0, 0);
                }
            }
        }
    }

    // ---- epilogue: transpose accs to [px 256][ch 64] bf16 in Au, coalesced NHWC store
    // C/D (16x16): col n = nb + nt*16 + l15; px-in-row = l4*4 + e; row = 4w + r.
    __syncthreads();
#pragma unroll
    for (int r = 0; r < 4; r++) {
        int pxl = ((w << 2) + r) * 16 + (l4 << 2);
#pragma unroll
        for (int nt = 0; nt < 4; nt++) {
            int nl = nt * 16 + l15;
#pragma unroll
            for (int e = 0; e < 4; e++)
                Au[(pxl + e) * 64 + nl] = f2b(acc[r * 4 + nt][e]);
        }
    }
    __syncthreads();
    short* outp = (short*)nh_out;
    for (int i = tid; i < 2048; i += 256) {   // 256 px x 8 seg
        int pxl = i >> 3, seg = i & 7;
        int y = ty0 + (pxl >> 4), x = tx0 + (pxl & 15);
        *(short8*)(outp + (bbase + y * WID + x) * NHWC_STRIDE + nb + seg * 8) =
            *(const short8*)&Au[pxl * 64 + seg * 8];
    }
    // BN partial sums: channel c = nhf*8 + nt*2 + (l15>>3)
#pragma unroll
    for (int nt = 0; nt < 4; nt++) {
        float sv = 0.f, s2v = 0.f;
#pragma unroll
        for (int r = 0; r < 4; r++)
#pragma unroll
            for (int e = 0; e < 4; e++) {
                float v = acc[r * 4 + nt][e];
                sv += v;
                s2v += v * v;
            }
#pragma unroll
        for (int off = 1; off <= 4; off <<= 1) {
            sv += __shfl_xor(sv, off);
            s2v += __shfl_xor(s2v, off);
        }
        sv += __shfl_xor(sv, 16);
        s2v += __shfl_xor(s2v, 16);
        sv += __shfl_xor(sv, 32);
        s2v += __shfl_xor(s2v, 32);
        if ((lane & 7) == 0 && l4 == 0) {
            int c = (nhf << 3) + (nt << 1) + (l15 >> 3);
            atomicAdd(&sred[c], sv);
            atomicAdd(&sred[16 + c], s2v);
        }
    }
    __syncthreads();
    if (tid < 16) {
        atomicAdd(&statsNew[tid * 2], sred[tid]);
        atomicAdd(&statsNew[tid * 2 + 1], sred[16 + tid]);
    }
}

// 1x1 gconv (R10..R13, unchanged): RAW NHWC in (BN+ReLU inline) -> bf16 planar + stats.
__global__ __launch_bounds__(256, 2) void conv1x1_gemm_k(const __hip_bfloat16* __restrict__ nh,
                                                         const __hip_bfloat16* __restrict__ B1h,
                                                         __hip_bfloat16* __restrict__ outP,
                                                         const float* __restrict__ statsPrev,
                                                         const float* __restrict__ gPrev,
                                                         const float* __restrict__ bPrev,
                                                         float* __restrict__ statsNew) {
    __shared__ float sred[32];
    __shared__ float ssl[32];
    const short* nhwc = (const short*)nh;
    const short* B1 = (const short*)B1h;
    int tid = threadIdx.x;
    if (tid < 32) sred[tid] = 0.f;
    if (tid < 16) {
        float mean = statsPrev[tid * 2] / BN_N;
        float var = statsPrev[tid * 2 + 1] / BN_N - mean * mean;
        float sc = gPrev[tid] * rsqrtf(var + 1e-5f);
        ssl[tid * 2] = sc;
        ssl[tid * 2 + 1] = bPrev[tid] - mean * sc;
    }
    __syncthreads();
    int b = blockIdx.y;
    int wave = tid >> 6, lane = tid & 63;
    int l31 = lane & 31, half = lane >> 5;
    int p0 = blockIdx.x * 256 + wave * 64;
    float16 acc[8];
#pragma unroll
    for (int i = 0; i < 8; i++) acc[i] = (float16)0.f;
    const short* a0p = nhwc + ((size_t)b * HW + p0 + l31) * NHWC_STRIDE + half * 8;
    const short* a1p = a0p + 32 * NHWC_STRIDE;
    const short* bp  = B1 + (size_t)l31 * 128 + half * 8;
#pragma unroll
    for (int ks = 0; ks < 8; ks++) {
        short8 r0 = *(const short8*)(a0p + ks * 16);
        short8 r1 = *(const short8*)(a1p + ks * 16);
        int c = ks * 2 + half;
        float sc = ssl[c * 2], sh = ssl[c * 2 + 1];
        short8 a0, a1;
#pragma unroll
        for (int e = 0; e < 8; e++) {
            a0[e] = f2b(fmaxf(fmaf(b2f(r0[e]), sc, sh), 0.f));
            a1[e] = f2b(fmaxf(fmaf(b2f(r1[e]), sc, sh), 0.f));
        }
#pragma unroll
        for (int nt = 0; nt < 4; nt++) {
            short8 bb = *(const short8*)(bp + nt * 32 * 128 + ks * 16);
            acc[nt]     = __builtin_amdgcn_mfma_f32_32x32x16_bf16(a0, bb, acc[nt], 0, 0, 0);
            acc[4 + nt] = __builtin_amdgcn_mfma_f32_32x32x16_bf16(a1, bb, acc[4 + nt], 0, 0, 0);
        }
    }
    short* outb = (short*)outP + (size_t)b * PLANE_B;
#pragma unroll
    for (int g = 0; g < 2; g++)
#pragma unroll
        for (int nt = 0; nt < 4; nt++) {
            int n = nt * 32 + l31;
#pragma unroll
            for (int r4 = 0; r4 < 4; r4++) {
                int base = 8 * r4 + 4 * half;
                short4v v;
                v[0] = f2b(acc[g * 4 + nt][r4 * 4 + 0]);
                v[1] = f2b(acc[g * 4 + nt][r4 * 4 + 1]);
                v[2] = f2b(acc[g * 4 + nt][r4 * 4 + 2]);
                v[3] = f2b(acc[g * 4 + nt][r4 * 4 + 3]);
                *(short4v*)(outb + (size_t)n * HW + p0 + g * 32 + base) = v;
            }
        }
    stats_reduce8(acc, lane, l31, sred);
    __syncthreads();
    if (tid < 16) {
        atomicAdd(&statsNew[tid * 2], sred[tid]);
        atomicAdd(&statsNew[tid * 2 + 1], sred[16 + tid]);
    }
}

// ---- BN-finalize + BN+ReLU on conv4 (bf16 planar), max over m, 1x1 + sigmoid ----
__global__ void final_k(const __hip_bfloat16* __restrict__ inP, const float* __restrict__ stats,
                        const float* __restrict__ g, const float* __restrict__ beta,
                        const float* __restrict__ fw, void* __restrict__ out,
                        const int* __restrict__ flag) {
    __shared__ float ssl[32];
    if (threadIdx.x < 16) {
        int c = threadIdx.x;
        float mean = stats[c * 2] / BN_N;
        float var = stats[c * 2 + 1] / BN_N - mean * mean;
        float sc = g[c] * rsqrtf(var + 1e-5f);
        ssl[c * 2] = sc;
        ssl[c * 2 + 1] = beta[c] - mean * sc;
    }
    __syncthreads();
    int i = blockIdx.x * blockDim.x + threadIdx.x;
    int b = i >> 16, pix = i & 65535;
    const short* inp = (const short*)inP;
    float acc = 0.f;
#pragma unroll
    for (int co = 0; co < 16; co++) {
        float sc = ssl[co * 2], sh = ssl[co * 2 + 1];
        float mx = 0.f;
        const short* p = inp + (size_t)b * PLANE_B + (size_t)co * PLANE_C + pix;
#pragma unroll
        for (int m = 0; m < 8; m++) mx = fmaxf(mx, fmaf(b2f(p[m * HW]), sc, sh));
        acc = fmaf(fw[co], mx, acc);
    }
    float r = 1.f / (1.f + expf(-acc));
    if (*flag)
        ((__hip_bfloat16*)out)[i] = __float2bfloat16(r);
    else
        ((float*)out)[i] = r;
}

extern "C" void kernel_launch(void* const* d_in, const int* in_sizes, int n_in,
                              void* d_out, int out_size, void* d_ws, size_t ws_size,
                              hipStream_t stream) {
    float* ws = (float*)d_ws;
    __hip_bfloat16* planarB = (__hip_bfloat16*)ws;              // 8,388,608 f
    __hip_bfloat16* nhwcA = (__hip_bfloat16*)(ws + 8388608);    // 8,912,896 f
    __hip_bfloat16* nhwcB = (__hip_bfloat16*)(ws + 17301504);   // 8,912,896 f
    __hip_bfloat16* Bg1   = (__hip_bfloat16*)(ws + 26214400);   // 204,800 f
    __hip_bfloat16* Bg2   = (__hip_bfloat16*)(ws + 26419200);   // 204,800 f
    __hip_bfloat16* Bg3   = (__hip_bfloat16*)(ws + 26624000);   // 204,800 f
    __hip_bfloat16* Blift = (__hip_bfloat16*)(ws + 26828800);   // 10,240 f
    __hip_bfloat16* B1    = (__hip_bfloat16*)(ws + 26839040);   // 8,192 f
    float* gbF  = ws + 26847232;       // 160
    float* fwF  = gbF + 160;           // 16
    float* statsL = fwF + 16;          // 5 x 32
    int*   flag   = (int*)(statsL + 160);

    detect_cvt_k<<<1, 256, 0, stream>>>(d_in[0], d_in[6],
                                        d_in[7], d_in[8], d_in[9], d_in[10], d_in[11],
                                        d_in[12], d_in[13], d_in[14], d_in[15], d_in[16],
                                        gbF, fwF, flag);

    mega_pack_k<<<(PK_TOTAL + 255) / 256, 256, 0, stream>>>(
        d_in[1], d_in[2], d_in[3], d_in[4], d_in[5],
        Blift, Bg1, Bg2, Bg3, B1, statsL, flag);

    lift_fused_k<<<dim3(256, 2), 256, 0, stream>>>(d_in[0], Blift, nhwcA, statsL, flag);

    __hip_bfloat16* Bgs[3] = {Bg1, Bg2, Bg3};
    __hip_bfloat16* nio[4] = {nhwcA, nhwcB, nhwcA, nhwcB};
    for (int l = 0; l < 3; l++) {
        gconv_mfma_k<<<1024, 256, 0, stream>>>(nio[l], Bgs[l], nio[l + 1],
                                               statsL + 32 * l, gbF + 32 * l, gbF + 32 * l + 16,
                                               statsL + 32 * (l + 1));
    }

    conv1x1_gemm_k<<<dim3(256, 2), 256, 0, stream>>>(nio[3], B1, planarB,
                                                     statsL + 96, gbF + 96, gbF + 112,
                                                     statsL + 128);

    final_k<<<(2 * HW) / 256, 256, 0, stream>>>(planarB, statsL + 128, gbF + 128, gbF + 144,
                                                fwF, d_out, flag);
}

// Round 15
// 458.144 us; speedup vs baseline: 1.3608x; 1.3608x over previous
//
#include <hip/hip_runtime.h>
#include <hip/hip_bf16.h>
#include <math.h>

// Between layers: NHWC bf16 RAW (pre-BN) [B][256*256][136] (ch=ci*8+o, pad->136).
// BN+ReLU applied during the NEXT layer's staging from fused batch stats.
#define HW 65536
#define WID 256
#define NOR 8
#define PLANE_C (NOR * HW)          // 524288
#define PLANE_B (16 * NOR * HW)     // 8388608
#define BN_N 1048576.0f
#define NHWC_STRIDE 136

typedef __attribute__((ext_vector_type(8)))  short  short8;
typedef __attribute__((ext_vector_type(4)))  short  short4v;
typedef __attribute__((ext_vector_type(16))) float  float16;
typedef __attribute__((ext_vector_type(4)))  float  float4v;

__device__ __forceinline__ float b2f(short s) {
    union { unsigned int u; float f; } c;
    c.u = ((unsigned int)(unsigned short)s) << 16;
    return c.f;
}
__device__ __forceinline__ short f2b(float f) {
    union { __hip_bfloat16 h; short s; } c;
    c.h = __float2bfloat16(f);
    return c.s;
}
__device__ __forceinline__ float ldv(const void* p, int i, int isbf) {
    return isbf ? b2f(((const short*)p)[i]) : ((const float*)p)[i];
}

// ---- detect dtype + convert the 176 BN/fw scalars (one block) ----
__global__ void detect_cvt_k(const void* x, const void* fw,
                             const void* g0, const void* b0, const void* g1, const void* b1,
                             const void* g2, const void* b2, const void* g3, const void* b3,
                             const void* g4, const void* b4,
                             float* __restrict__ gbF, float* __restrict__ fwF,
                             int* __restrict__ flag) {
    __shared__ int bad;
    if (threadIdx.x == 0) bad = 0;
    __syncthreads();
    const __hip_bfloat16* p = (const __hip_bfloat16*)x;
    for (int i = threadIdx.x; i < 4096; i += 256) {
        float v = __bfloat162float(p[i]);
        if (!(fabsf(v) < 1e4f)) atomicOr(&bad, 1);
    }
    __syncthreads();
    int isbf = bad ? 0 : 1;
    if (threadIdx.x == 0) *flag = isbf;
    int t = threadIdx.x;
    if (t < 160) {
        const void* srcs[10] = {g0, b0, g1, b1, g2, b2, g3, b3, g4, b4};
        gbF[t] = ldv(srcs[t >> 4], t & 15, isbf);
    } else if (t < 176) {
        fwF[t - 160] = ldv(fw, t - 160, isbf);
    }
}

// ---- bilinear kernel rotation, flag-branched source (same math as R2..R14) ----
__device__ float rot_sample_g(const void* __restrict__ W, int isbf, int k, float theta,
                              int i, int j) {
    float c = 0.5f * (float)(k - 1);
    float ys = (float)i - c, xs = (float)j - c;
    float cs = cosf(theta), sn = sinf(theta);
    float sy = cs * ys - sn * xs + c;
    float sx = sn * ys + cs * xs + c;
    float fy = floorf(sy), fx = floorf(sx);
    int y0 = (int)fy, x0 = (int)fx;
    float wy = sy - fy, wx = sx - fx;
    float v00 = (y0 >= 0 && y0 < k && x0 >= 0 && x0 < k)                 ? ldv(W, y0 * k + x0, isbf)           : 0.f;
    float v01 = (y0 >= 0 && y0 < k && x0 + 1 >= 0 && x0 + 1 < k)         ? ldv(W, y0 * k + x0 + 1, isbf)       : 0.f;
    float v10 = (y0 + 1 >= 0 && y0 + 1 < k && x0 >= 0 && x0 < k)         ? ldv(W, (y0 + 1) * k + x0, isbf)     : 0.f;
    float v11 = (y0 + 1 >= 0 && y0 + 1 < k && x0 + 1 >= 0 && x0 + 1 < k) ? ldv(W, (y0 + 1) * k + x0 + 1, isbf) : 0.f;
    return v00 * (1 - wy) * (1 - wx) + v01 * (1 - wy) * wx
         + v10 * wy * (1 - wx) + v11 * wy * wx;
}

__device__ __forceinline__ float theta_of(int m) {
    return (6.2831855f * (float)m) / 8.0f;
}

__device__ __forceinline__ int mirror(int i) {
    i = i < 0 ? -i : i;
    return i >= WID ? (2 * WID - 2 - i) : i;
}

// ---- MEGA-PACK (flag-branched raw weights) + all 5 layer stats zeroed ----
// Blift[n=c*8+o][k=ci*49+s pad 160]; Bg[q(4)][s(25)][kc4(4)][n(128)][j(8)],
// ch=q*32+kc4*8+j; B1[n][ch].
#define PK_BLIFT 20480
#define PK_BG 409600
#define PK_TOTAL (PK_BLIFT + 3 * PK_BG + 16384)
__global__ void mega_pack_k(const void* __restrict__ lw, const void* __restrict__ w1,
                            const void* __restrict__ w2, const void* __restrict__ w3,
                            const void* __restrict__ w4,
                            __hip_bfloat16* __restrict__ Blift, __hip_bfloat16* __restrict__ Bg1,
                            __hip_bfloat16* __restrict__ Bg2, __hip_bfloat16* __restrict__ Bg3,
                            __hip_bfloat16* __restrict__ B1, float* __restrict__ statsL,
                            const int* __restrict__ flag) {
    int idx = blockIdx.x * 256 + threadIdx.x;
    if (idx < 160) statsL[idx] = 0.f;
    if (idx >= PK_TOTAL) return;
    int isbf = *flag;
    if (idx < PK_BLIFT) {
        int n = idx / 160, k = idx % 160;
        float v = 0.f;
        if (k < 147) {
            int c = n >> 3, o = n & 7;
            int ci = k / 49, s = k % 49;
            v = rot_sample_g(isbf ? (const void*)((const short*)lw + (c * 3 + ci) * 49)
                                  : (const void*)((const float*)lw + (c * 3 + ci) * 49),
                             isbf, 7, theta_of(o), s / 7, s % 7);
        }
        Blift[idx] = __float2bfloat16(v);
        return;
    }
    idx -= PK_BLIFT;
    if (idx < 3 * PK_BG) {
        int l = idx / PK_BG;
        int r = idx - l * PK_BG;
        const void* w = (l == 0) ? w1 : ((l == 1) ? w2 : w3);
        __hip_bfloat16* Bg = (l == 0) ? Bg1 : ((l == 1) ? Bg2 : Bg3);
        int j = r & 7;
        int n = (r >> 3) & 127;
        int kc4 = (r >> 10) & 3;
        int sq = r >> 12;
        int s = sq % 25, q = sq / 25;
        int ch = q * 32 + kc4 * 8 + j;
        int co = n >> 3, m = n & 7, ci = ch >> 3, o = ch & 7;
        int oo = (o - m + 8) & 7;
        int off = ((co * 16 + ci) * 8 + oo) * 25;
        const void* wp = isbf ? (const void*)((const short*)w + off)
                              : (const void*)((const float*)w + off);
        Bg[r] = __float2bfloat16(rot_sample_g(wp, isbf, 5, theta_of(m), s / 5, s % 5));
        return;
    }
    idx -= 3 * PK_BG;
    {
        int n = idx >> 7, ch = idx & 127;
        int co = n >> 3, m = n & 7, ci = ch >> 3, o = ch & 7;
        B1[idx] = __float2bfloat16(ldv(w4, (co * 16 + ci) * 8 + ((o - m + 8) & 7), isbf));
    }
}

// BN partial-sum reduction (8-acc 32x32 variant), verified R6..R14.
__device__ __forceinline__ void stats_reduce8(const float16* acc, int lane, int l31,
                                              float* sred) {
#pragma unroll
    for (int nt = 0; nt < 4; nt++) {
        float sv = 0.f, s2v = 0.f;
#pragma unroll
        for (int g = 0; g < 2; g++)
#pragma unroll
            for (int r = 0; r < 16; r++) {
                float v = acc[g * 4 + nt][r];
                sv += v;
                s2v += v * v;
            }
#pragma unroll
        for (int off = 1; off <= 4; off <<= 1) {
            sv += __shfl_xor(sv, off);
            s2v += __shfl_xor(s2v, off);
        }
        sv += __shfl_xor(sv, 32);
        s2v += __shfl_xor(s2v, 32);
        if ((lane & 39) == 0) {
            int c = nt * 4 + (l31 >> 3);
            atomicAdd(&sred[c], sv);
            atomicAdd(&sred[16 + c], s2v);
        }
    }
}

// ---- FUSED lift (R11/R13, unchanged) ----
__global__ __launch_bounds__(256, 2) void lift_fused_k(const void* __restrict__ x,
                                                       const __hip_bfloat16* __restrict__ Bh,
                                                       __hip_bfloat16* __restrict__ nh_out,
                                                       float* __restrict__ stats,
                                                       const int* __restrict__ flag) {
    __shared__ float Xs[3 * 484];
    __shared__ short tb[32768];
    __shared__ float sred[32];
    const short* B = (const short*)Bh;
    int tid = threadIdx.x;
    if (tid < 32) sred[tid] = 0.f;
    int isbf = *flag;
    int tile = blockIdx.x;
    int b = blockIdx.y;
    int tx0 = (tile & 15) << 4, ty0 = (tile >> 4) << 4;
    for (int i = tid; i < 1452; i += 256) {
        int ci = i / 484, p = i - ci * 484;
        int yl = p / 22, xl = p - yl * 22;
        int gy = mirror(ty0 - 3 + yl), gx = mirror(tx0 - 3 + xl);
        Xs[i] = ldv(x, (int)(((size_t)b * 3 + ci) * HW) + gy * WID + gx, isbf);
    }
    __syncthreads();
    int wave = tid >> 6, lane = tid & 63;
    int l31 = lane & 31, half = lane >> 5;
    float16 acc[8];
#pragma unroll
    for (int i = 0; i < 8; i++) acc[i] = (float16)0.f;
    int pxl0 = wave * 64 + l31;
    int py0 = pxl0 >> 4, px0 = pxl0 & 15;
    int py1 = (pxl0 + 32) >> 4, px1 = (pxl0 + 32) & 15;
    const short* bp = B + (size_t)l31 * 160 + half * 8;
#pragma unroll
    for (int ks = 0; ks < 10; ks++) {
        short8 a0, a1;
#pragma unroll
        for (int j = 0; j < 8; j++) {
            int k = ks * 16 + half * 8 + j;
            float v0 = 0.f, v1 = 0.f;
            if (k < 147) {
                int ci = (k < 49) ? 0 : ((k < 98) ? 1 : 2);
                int s = k - ci * 49;
                int sy = s / 7, sx = s - sy * 7;
                v0 = Xs[ci * 484 + (py0 + sy) * 22 + px0 + sx];
                v1 = Xs[ci * 484 + (py1 + sy) * 22 + px1 + sx];
            }
            a0[j] = f2b(v0);
            a1[j] = f2b(v1);
        }
#pragma unroll
        for (int nt = 0; nt < 4; nt++) {
            short8 bb = *(const short8*)(bp + nt * 32 * 160 + ks * 16);
            acc[nt]     = __builtin_amdgcn_mfma_f32_32x32x16_bf16(a0, bb, acc[nt], 0, 0, 0);
            acc[4 + nt] = __builtin_amdgcn_mfma_f32_32x32x16_bf16(a1, bb, acc[4 + nt], 0, 0, 0);
        }
    }
#pragma unroll
    for (int g = 0; g < 2; g++)
#pragma unroll
        for (int nt = 0; nt < 4; nt++) {
            int ch = nt * 32 + l31;
#pragma unroll
            for (int r4 = 0; r4 < 4; r4++) {
                int pxb = wave * 64 + g * 32 + 8 * r4 + 4 * half;
#pragma unroll
                for (int i = 0; i < 4; i++)
                    tb[(pxb + i) * 128 + ch] = f2b(acc[g * 4 + nt][r4 * 4 + i]);
            }
        }
    __syncthreads();
    short* outp = (short*)nh_out + (size_t)b * HW * NHWC_STRIDE;
    for (int i = tid; i < 4096; i += 256) {
        int pxl = i >> 4, seg = i & 15;
        int y = ty0 + (pxl >> 4), xx = tx0 + (pxl & 15);
        *(short8*)(outp + ((size_t)y * WID + xx) * NHWC_STRIDE + seg * 8) =
            *(const short8*)&tb[pxl * 128 + seg * 8];
    }
    stats_reduce8(acc, lane, l31, sred);
    __syncthreads();
    if (tid < 16) {
        atomicAdd(&stats[tid * 2], sred[tid]);
        atomicAdd(&stats[tid * 2 + 1], sred[16 + tid]);
    }
}

// gconv GEMM (R12 exact — measured best: 106 µs, MfmaUtil 43%): grid 512,
// block = 256 thr = 4 waves; wave = 128 px (8 rows x 16) x 64 n, 8x4 acc
// (128 AGPR). A-halo per kh-HALF (64 ch) in 64 KB LDS union; B via L1;
// barrier-free s-loop; BN(prev) at staging; raw NHWC out; fused stats.
// R13 (dx-outer a[12], VGPR 128) and R14 (64-n blocks, 3/CU) both regressed.
__global__ __launch_bounds__(256, 2) void gconv_mfma_k(const __hip_bfloat16* __restrict__ nh_in,
                                                       const __hip_bfloat16* __restrict__ Bgh,
                                                       __hip_bfloat16* __restrict__ nh_out,
                                                       const float* __restrict__ statsPrev,
                                                       const float* __restrict__ gPrev,
                                                       const float* __restrict__ bPrev,
                                                       float* __restrict__ statsNew) {
    __shared__ short Au[32768];   // union: halo [kc8][441][8] (28040 used) | transpose [256][128]
    __shared__ float ssl[32];
    __shared__ float sred[32];
    const short* nhwc = (const short*)nh_in;
    const short* Bg = (const short*)Bgh;
    int bid = blockIdx.x;              // 0..511
    int xcd = bid & 7, qt = bid >> 3;
    int b = xcd >> 2, band = xcd & 3;
    int tx0 = (qt & 15) << 4;
    int ty0 = (band << 6) + ((qt >> 4) << 4);
    int tid = threadIdx.x;
    if (tid < 32) sred[tid] = 0.f;
    if (tid < 16) {
        float mean = statsPrev[tid * 2] / BN_N;
        float var = statsPrev[tid * 2 + 1] / BN_N - mean * mean;
        float sc = gPrev[tid] * rsqrtf(var + 1e-5f);
        ssl[tid * 2] = sc;
        ssl[tid * 2 + 1] = bPrev[tid] - mean * sc;
    }
    int w = tid >> 6, lane = tid & 63;
    int pxg = w & 1, nhf = w >> 1;
    int l15 = lane & 15, l4 = lane >> 4;
    float4v acc[32];
#pragma unroll
    for (int i = 0; i < 32; i++) acc[i] = (float4v)0.f;
    const size_t bbase = (size_t)b * HW;
    const int nb = nhf << 6;

    for (int h = 0; h < 2; h++) {
        __syncthreads();
        for (int i = tid; i < 3200; i += 256) {
            int kc = i / 400, p = i - kc * 400;
            int yl = p / 20, xl = p - yl * 20;
            int gy = mirror(ty0 - 2 + yl);
            int gx = mirror(tx0 - 2 + xl);
            short8 raw = *(const short8*)(nhwc + (bbase + gy * WID + gx) * NHWC_STRIDE
                                          + h * 64 + kc * 8);
            int c = h * 8 + kc;
            float sc = ssl[c * 2], sh = ssl[c * 2 + 1];
            short8 ov;
#pragma unroll
            for (int e = 0; e < 8; e++)
                ov[e] = f2b(fmaxf(fmaf(b2f(raw[e]), sc, sh), 0.f));
            *(short8*)&Au[(kc * 441 + yl * 21 + xl) * 8] = ov;
        }
        __syncthreads();
        for (int s = 0; s < 25; s++) {
            int dy = s / 5 - 2, dx = s % 5 - 2;
#pragma unroll
            for (int kq = 0; kq < 2; kq++) {
                int abase = (kq * 4 + l4) * 441 + ((pxg << 3) + 2 + dy) * 21 + (l15 + 2 + dx);
                const short* brow = Bg
                    + ((size_t)(((((h * 2 + kq) * 25 + s) << 2) + l4)) * 128 + nb + l15) * 8;
                short8 a[8];
#pragma unroll
                for (int r = 0; r < 8; r++)
                    a[r] = *(const short8*)&Au[(abase + r * 21) * 8];
#pragma unroll
                for (int nt = 0; nt < 4; nt++) {
                    short8 bb = *(const short8*)(brow + nt * 128);
#pragma unroll
                    for (int r = 0; r < 8; r++)
                        acc[r * 4 + nt] = __builtin_amdgcn_mfma_f32_16x16x32_bf16(
                            a[r], bb, acc[r * 4 + nt], 0, 0, 0);
                }
            }
        }
    }

    // ---- epilogue: transpose accs to [px 256][ch 128] bf16 in Au, coalesced NHWC store
    __syncthreads();
#pragma unroll
    for (int r = 0; r < 8; r++) {
        int pxl = ((pxg << 3) + r) * 16 + (l4 << 2);
#pragma unroll
        for (int nt = 0; nt < 4; nt++) {
            int n = nb + nt * 16 + l15;
#pragma unroll
            for (int e = 0; e < 4; e++)
                Au[(pxl + e) * 128 + n] = f2b(acc[r * 4 + nt][e]);
        }
    }
    __syncthreads();
    short* outp = (short*)nh_out;
    for (int i = tid; i < 4096; i += 256) {
        int pxl = i >> 4, seg = i & 15;
        int y = ty0 + (pxl >> 4), x = tx0 + (pxl & 15);
        *(short8*)(outp + (bbase + y * WID + x) * NHWC_STRIDE + seg * 8) =
            *(const short8*)&Au[pxl * 128 + seg * 8];
    }
    // BN partial sums: channel c = nhf*8 + nt*2 + (l15>>3)
#pragma unroll
    for (int nt = 0; nt < 4; nt++) {
        float sv = 0.f, s2v = 0.f;
#pragma unroll
        for (int r = 0; r < 8; r++)
#pragma unroll
            for (int e = 0; e < 4; e++) {
                float v = acc[r * 4 + nt][e];
                sv += v;
                s2v += v * v;
            }
#pragma unroll
        for (int off = 1; off <= 4; off <<= 1) {
            sv += __shfl_xor(sv, off);
            s2v += __shfl_xor(s2v, off);
        }
        sv += __shfl_xor(sv, 16);
        s2v += __shfl_xor(s2v, 16);
        sv += __shfl_xor(sv, 32);
        s2v += __shfl_xor(s2v, 32);
        if ((lane & 7) == 0 && l4 == 0) {
            int c = (nhf << 3) + (nt << 1) + (l15 >> 3);
            atomicAdd(&sred[c], sv);
            atomicAdd(&sred[16 + c], s2v);
        }
    }
    __syncthreads();
    if (tid < 16) {
        atomicAdd(&statsNew[tid * 2], sred[tid]);
        atomicAdd(&statsNew[tid * 2 + 1], sred[16 + tid]);
    }
}

// 1x1 gconv (R10..R14, unchanged): RAW NHWC in (BN+ReLU inline) -> bf16 planar + stats.
__global__ __launch_bounds__(256, 2) void conv1x1_gemm_k(const __hip_bfloat16* __restrict__ nh,
                                                         const __hip_bfloat16* __restrict__ B1h,
                                                         __hip_bfloat16* __restrict__ outP,
                                                         const float* __restrict__ statsPrev,
                                                         const float* __restrict__ gPrev,
                                                         const float* __restrict__ bPrev,
                                                         float* __restrict__ statsNew) {
    __shared__ float sred[32];
    __shared__ float ssl[32];
    const short* nhwc = (const short*)nh;
    const short* B1 = (const short*)B1h;
    int tid = threadIdx.x;
    if (tid < 32) sred[tid] = 0.f;
    if (tid < 16) {
        float mean = statsPrev[tid * 2] / BN_N;
        float var = statsPrev[tid * 2 + 1] / BN_N - mean * mean;
        float sc = gPrev[tid] * rsqrtf(var + 1e-5f);
        ssl[tid * 2] = sc;
        ssl[tid * 2 + 1] = bPrev[tid] - mean * sc;
    }
    __syncthreads();
    int b = blockIdx.y;
    int wave = tid >> 6, lane = tid & 63;
    int l31 = lane & 31, half = lane >> 5;
    int p0 = blockIdx.x * 256 + wave * 64;
    float16 acc[8];
#pragma unroll
    for (int i = 0; i < 8; i++) acc[i] = (float16)0.f;
    const short* a0p = nhwc + ((size_t)b * HW + p0 + l31) * NHWC_STRIDE + half * 8;
    const short* a1p = a0p + 32 * NHWC_STRIDE;
    const short* bp  = B1 + (size_t)l31 * 128 + half * 8;
#pragma unroll
    for (int ks = 0; ks < 8; ks++) {
        short8 r0 = *(const short8*)(a0p + ks * 16);
        short8 r1 = *(const short8*)(a1p + ks * 16);
        int c = ks * 2 + half;
        float sc = ssl[c * 2], sh = ssl[c * 2 + 1];
        short8 a0, a1;
#pragma unroll
        for (int e = 0; e < 8; e++) {
            a0[e] = f2b(fmaxf(fmaf(b2f(r0[e]), sc, sh), 0.f));
            a1[e] = f2b(fmaxf(fmaf(b2f(r1[e]), sc, sh), 0.f));
        }
#pragma unroll
        for (int nt = 0; nt < 4; nt++) {
            short8 bb = *(const short8*)(bp + nt * 32 * 128 + ks * 16);
            acc[nt]     = __builtin_amdgcn_mfma_f32_32x32x16_bf16(a0, bb, acc[nt], 0, 0, 0);
            acc[4 + nt] = __builtin_amdgcn_mfma_f32_32x32x16_bf16(a1, bb, acc[4 + nt], 0, 0, 0);
        }
    }
    short* outb = (short*)outP + (size_t)b * PLANE_B;
#pragma unroll
    for (int g = 0; g < 2; g++)
#pragma unroll
        for (int nt = 0; nt < 4; nt++) {
            int n = nt * 32 + l31;
#pragma unroll
            for (int r4 = 0; r4 < 4; r4++) {
                int base = 8 * r4 + 4 * half;
                short4v v;
                v[0] = f2b(acc[g * 4 + nt][r4 * 4 + 0]);
                v[1] = f2b(acc[g * 4 + nt][r4 * 4 + 1]);
                v[2] = f2b(acc[g * 4 + nt][r4 * 4 + 2]);
                v[3] = f2b(acc[g * 4 + nt][r4 * 4 + 3]);
                *(short4v*)(outb + (size_t)n * HW + p0 + g * 32 + base) = v;
            }
        }
    stats_reduce8(acc, lane, l31, sred);
    __syncthreads();
    if (tid < 16) {
        atomicAdd(&statsNew[tid * 2], sred[tid]);
        atomicAdd(&statsNew[tid * 2 + 1], sred[16 + tid]);
    }
}

// ---- BN-finalize + BN+ReLU on conv4 (bf16 planar), max over m, 1x1 + sigmoid ----
__global__ void final_k(const __hip_bfloat16* __restrict__ inP, const float* __restrict__ stats,
                        const float* __restrict__ g, const float* __restrict__ beta,
                        const float* __restrict__ fw, void* __restrict__ out,
                        const int* __restrict__ flag) {
    __shared__ float ssl[32];
    if (threadIdx.x < 16) {
        int c = threadIdx.x;
        float mean = stats[c * 2] / BN_N;
        float var = stats[c * 2 + 1] / BN_N - mean * mean;
        float sc = g[c] * rsqrtf(var + 1e-5f);
        ssl[c * 2] = sc;
        ssl[c * 2 + 1] = beta[c] - mean * sc;
    }
    __syncthreads();
    int i = blockIdx.x * blockDim.x + threadIdx.x;
    int b = i >> 16, pix = i & 65535;
    const short* inp = (const short*)inP;
    float acc = 0.f;
#pragma unroll
    for (int co = 0; co < 16; co++) {
        float sc = ssl[co * 2], sh = ssl[co * 2 + 1];
        float mx = 0.f;
        const short* p = inp + (size_t)b * PLANE_B + (size_t)co * PLANE_C + pix;
#pragma unroll
        for (int m = 0; m < 8; m++) mx = fmaxf(mx, fmaf(b2f(p[m * HW]), sc, sh));
        acc = fmaf(fw[co], mx, acc);
    }
    float r = 1.f / (1.f + expf(-acc));
    if (*flag)
        ((__hip_bfloat16*)out)[i] = __float2bfloat16(r);
    else
        ((float*)out)[i] = r;
}

extern "C" void kernel_launch(void* const* d_in, const int* in_sizes, int n_in,
                              void* d_out, int out_size, void* d_ws, size_t ws_size,
                              hipStream_t stream) {
    float* ws = (float*)d_ws;
    __hip_bfloat16* planarB = (__hip_bfloat16*)ws;              // 8,388,608 f
    __hip_bfloat16* nhwcA = (__hip_bfloat16*)(ws + 8388608);    // 8,912,896 f
    __hip_bfloat16* nhwcB = (__hip_bfloat16*)(ws + 17301504);   // 8,912,896 f
    __hip_bfloat16* Bg1   = (__hip_bfloat16*)(ws + 26214400);   // 204,800 f
    __hip_bfloat16* Bg2   = (__hip_bfloat16*)(ws + 26419200);   // 204,800 f
    __hip_bfloat16* Bg3   = (__hip_bfloat16*)(ws + 26624000);   // 204,800 f
    __hip_bfloat16* Blift = (__hip_bfloat16*)(ws + 26828800);   // 10,240 f
    __hip_bfloat16* B1    = (__hip_bfloat16*)(ws + 26839040);   // 8,192 f
    float* gbF  = ws + 26847232;       // 160
    float* fwF  = gbF + 160;           // 16
    float* statsL = fwF + 16;          // 5 x 32
    int*   flag   = (int*)(statsL + 160);

    detect_cvt_k<<<1, 256, 0, stream>>>(d_in[0], d_in[6],
                                        d_in[7], d_in[8], d_in[9], d_in[10], d_in[11],
                                        d_in[12], d_in[13], d_in[14], d_in[15], d_in[16],
                                        gbF, fwF, flag);

    mega_pack_k<<<(PK_TOTAL + 255) / 256, 256, 0, stream>>>(
        d_in[1], d_in[2], d_in[3], d_in[4], d_in[5],
        Blift, Bg1, Bg2, Bg3, B1, statsL, flag);

    lift_fused_k<<<dim3(256, 2), 256, 0, stream>>>(d_in[0], Blift, nhwcA, statsL, flag);

    __hip_bfloat16* Bgs[3] = {Bg1, Bg2, Bg3};
    __hip_bfloat16* nio[4] = {nhwcA, nhwcB, nhwcA, nhwcB};
    for (int l = 0; l < 3; l++) {
        gconv_mfma_k<<<512, 256, 0, stream>>>(nio[l], Bgs[l], nio[l + 1],
                                              statsL + 32 * l, gbF + 32 * l, gbF + 32 * l + 16,
                                              statsL + 32 * (l + 1));
    }

    conv1x1_gemm_k<<<dim3(256, 2), 256, 0, stream>>>(nio[3], B1, planarB,
                                                     statsL + 96, gbF + 96, gbF + 112,
                                                     statsL + 128);

    final_k<<<(2 * HW) / 256, 256, 0, stream>>>(planarB, statsL + 128, gbF + 128, gbF + 144,
                                                fwF, d_out, flag);
}